// Round 5
// baseline (126.320 us; speedup 1.0000x reference)
//
#include <hip/hip_runtime.h>
#include <cstdint>

#define L_SEQ 2048
#define NH 16
#define EDIM 64
#define WINDOW 1024
#define QT 64
#define KT 64
#define LOG2E 1.4426950408889634f
#define M_FIX 16.0f   // fixed softmax max in log2 domain (scores bounded ~|10|)

typedef short bf16x8 __attribute__((ext_vector_type(8)));
typedef short bf16x4 __attribute__((ext_vector_type(4)));
typedef float f32x4 __attribute__((ext_vector_type(4)));

__device__ __forceinline__ short f2bf(float x) {   // RNE
    uint32_t u = __builtin_bit_cast(uint32_t, x);
    uint32_t r = (u + 0x7fffu + ((u >> 16) & 1u)) >> 16;
    return (short)(r & 0xffffu);
}
__device__ __forceinline__ short f2bf_trunc(float x) {
    return (short)(__builtin_bit_cast(uint32_t, x) >> 16);
}

// 16x16x16 bf16 MFMA: builtin when the toolchain has it, else raw asm
__device__ __forceinline__ f32x4 mfma16(bf16x4 a, bf16x4 b, f32x4 c) {
#if __has_builtin(__builtin_amdgcn_mfma_f32_16x16x16bf16_1k)
    return __builtin_amdgcn_mfma_f32_16x16x16bf16_1k(a, b, c, 0, 0, 0);
#else
    asm("s_nop 1\n\tv_mfma_f32_16x16x16_bf16 %0, %1, %2, %0"
        : "+v"(c) : "v"(a), "v"(b));
    return c;
#endif
}

// async 16B/lane global->LDS: LDS dest = wave-uniform base + lane*16 (m104/m108)
__device__ __forceinline__ void async16(const short* g, const short* l) {
    __builtin_amdgcn_global_load_lds(
        (const __attribute__((address_space(1))) void*)(uintptr_t)(g),
        (__attribute__((address_space(3))) void*)(uintptr_t)(l),
        16, 0, 0);
}

// counted-vmcnt sync point: newest 2 DMAs stay in flight across the barrier.
// Canonical form (rule #18): asm waitcnt -> builtin barrier -> sched_barrier(0).
#define SYNC_VMCNT2()                                           \
    do {                                                        \
        asm volatile("s_waitcnt vmcnt(2)" ::: "memory");        \
        __builtin_amdgcn_s_barrier();                           \
        __builtin_amdgcn_sched_barrier(0);                      \
    } while (0)

// ---------------- prepass: K + V only (Q loaded fp32 by attn) ----------------
//  XCD-local to consumer: attn blocks on XCD x read pairs 4x..4x+3 -> convert
//  pair p on XCD p>>2 so the 2 MB/XCD bf16 K+V stays in the consumer's L2.
//  Also zeroes the 8 per-XCD work-queue counters (blocks x<8 run on XCD x).
//  K chunk c : row=c>>3, cc=(c&7)^(row&7) : K[row][cc*8 + j]   (XOR swizzle)
//  V chunk c = et*128 + a*64 + quad*16 + r16 :
//      j 0..3 -> V[a*32 + quad*4 + j][et*16 + r16]
//      j 4..7 -> V[a*32 + 16 + quad*4 + (j-4)][et*16 + r16]
__global__ __launch_bounds__(256) void prepass5(const float* __restrict__ qkv,
        short* __restrict__ kw, short* __restrict__ vw, int* __restrict__ cnt) {
    __shared__ float vt[64][68];   // vt[e][row]; 272 B rows -> 16B-aligned float4
    const int x = blockIdx.x;      // 1024 blocks
    if (x < 8 && threadIdx.x == 0) cnt[x] = 0;   // zero this XCD's queue counter
    const int xcd = x & 7, y = x >> 3;
    const int pairid = xcd * 4 + (y >> 5);   // pairs 4x..4x+3 on XCD x
    const int tile = y & 31;
    const int b = pairid >> 4, h = pairid & 15;
    const int tid = threadIdx.x;
    const int tg = pairid * 32 + tile;
    const float* base = qkv + (size_t)b * (L_SEQ * 3072) + (size_t)tile * 64 * 3072 + h * 64;
    short* ko = kw + (size_t)tg * 4096;
    short* vo = vw + (size_t)tg * 4096;

    // K (XOR-swizzled chunk order)
    #pragma unroll
    for (int it = 0; it < 2; ++it) {
        const int c = tid + it * 256;
        const int row = c >> 3, cc = (c & 7) ^ (row & 7);
        const float* src = base + (size_t)row * 3072 + 1024 + cc * 8;
        float4 a = *(const float4*)src, d = *(const float4*)(src + 4);
        short* o = ko + (size_t)c * 8;
        o[0] = f2bf(a.x); o[1] = f2bf(a.y); o[2] = f2bf(a.z); o[3] = f2bf(a.w);
        o[4] = f2bf(d.x); o[5] = f2bf(d.y); o[6] = f2bf(d.z); o[7] = f2bf(d.w);
    }
    // V: coalesced row reads -> transposed LDS
    {
        const int row = tid >> 2, e0 = (tid & 3) << 4;
        const float* src = base + (size_t)row * 3072 + 2048 + e0;
        #pragma unroll
        for (int q4 = 0; q4 < 4; ++q4) {
            float4 a = *(const float4*)(src + q4 * 4);
            vt[e0 + q4 * 4 + 0][row] = a.x;
            vt[e0 + q4 * 4 + 1][row] = a.y;
            vt[e0 + q4 * 4 + 2][row] = a.z;
            vt[e0 + q4 * 4 + 3][row] = a.w;
        }
    }
    __syncthreads();
    #pragma unroll
    for (int it = 0; it < 2; ++it) {
        const int c = tid + it * 256;
        const int et = c >> 7, a = (c >> 6) & 1, l6 = c & 63;
        const int quad = l6 >> 4, r16 = l6 & 15;
        const int e = et * 16 + r16;
        float4 x0 = *(const float4*)&vt[e][a * 32 + quad * 4];
        float4 x1 = *(const float4*)&vt[e][a * 32 + 16 + quad * 4];
        bf16x8 o8;
        o8[0] = f2bf(x0.x); o8[1] = f2bf(x0.y); o8[2] = f2bf(x0.z); o8[3] = f2bf(x0.w);
        o8[4] = f2bf(x1.x); o8[5] = f2bf(x1.y); o8[6] = f2bf(x1.z); o8[7] = f2bf(x1.w);
        *(bf16x8*)(vo + (size_t)c * 8) = o8;
    }
}

// ---------------- attention v10: per-XCD dynamic work queue ----------------
// v8b post-mortem: every in-loop scheduling fix (v7 2D split, v8 counted
// vmcnt) left attn at ~38-40 us; v6's counters showed Occupancy 15%/25%,
// MfmaUtil 17% -> the stall is BETWEEN blocks: static block->CU pinning
// balances the per-CU SUM (51 tiles) but not the MAKESPAN ({17,17,16,1} ->
// the n=1 block dies instantly, no refill, CU decays to 2-3 blocks).
// v10: 512-thr/8-wave blocks, grid (8,64) = 2 blocks/CU (16 waves/CU), and a
// per-XCD atomic queue of 128 items (4 pairs x 32 qtiles) over 64 workers ->
// finished blocks immediately pull the next item; CUs stay full until the
// queue drains. Items are complete (pair,qtile): no cross-block combine, no
// DMA duplication; XCD-L2 locality preserved. Longest-first (qtile 31->0).
// Wave layout: qhalf=w&1 (32 q rows, 2 MFMA groups - K/V LDS reuse kept),
// kq=w>>1 (16-key quarter). k-loop = v8b's 3-slot K / 2-slot V counted-vmcnt
// pipeline at 1 DMA/wave/buffer (vmcnt(2)). Epilogue: 3-step LDS tree combine
// of the 4 kq partials (exact: fixed-max softmax partials add).
__global__ __launch_bounds__(512, 4) void flexattn_fwd10(
        const float* __restrict__ qkv, const short* __restrict__ kw,
        const short* __restrict__ vw, int* __restrict__ cnt,
        float* __restrict__ out) {
    __shared__ __align__(16) short smem[5 * 4096];   // 40 KB: K 3-slot + V 2-slot
    __shared__ int itemS;
    short (*kB)[4096]  = (short (*)[4096])&smem[0];
    short (*vB2)[4096] = (short (*)[4096])&smem[3 * 4096];

    const int xq   = blockIdx.x;     // linear%8 == XCD (grid (8,64))
    const int tid  = threadIdx.x;    // 0..511
    const int w    = tid >> 6;       // wave 0..7
    const int lane = tid & 63;
    const int quad = lane >> 4;
    const int r16  = lane & 15;
    const int qhalf = w & 1;         // which 32 q rows of the 64-q tile
    const int kq    = w >> 1;        // which 16-key quarter of each 64-k tile
    const int swz  = quad ^ (r16 & 7);
    const int cb0  = w * 64;         // this wave's 64 chunks (of 512) per tile

    for (;;) {
        if (tid == 0) itemS = atomicAdd(&cnt[xq], 1);
        __syncthreads();              // publish itemS (also full drain)
        const int item = itemS;
        if (item >= 128) return;      // block-uniform exit

        const int pairid = xq * 4 + (item & 3);
        const int qtile  = 31 - (item >> 2);        // longest-first
        const int h  = pairid & 15;
        const int b  = pairid >> 4;
        const int qb = qtile * QT;
        const int bh32 = pairid * 32;
        const int q0 = qb + qhalf * 32 + r16;       // group-0 query; group-1 = +16
        const int t0q = (qb >= WINDOW - 1) ? ((qb - (WINDOW - 1)) >> 6) : 0;
        const int t1  = qtile;

        // ---- Q raw loads FIRST (their consume-wait leaves DMAs in flight)
        float4 qraw[2][2][2];
        #pragma unroll
        for (int g = 0; g < 2; ++g) {
            const float* qrow = qkv + (size_t)b * (L_SEQ * 3072)
                                    + (size_t)(q0 + g * 16) * 3072 + h * 64;
            #pragma unroll
            for (int es = 0; es < 2; ++es) {
                const float* p = qrow + es * 32 + quad * 8;
                qraw[g][es][0] = *(const float4*)p;
                qraw[g][es][1] = *(const float4*)(p + 4);
            }
        }

        // ---- prologue DMA (1 instr/wave/buffer; issue order = vmcnt FIFO):
        //      K(t0), K(t0+1 clamped), V(t0)
        {
            const int t0c1 = (t0q + 1 <= t1) ? t0q + 1 : t1;
            const short* k0t = kw + (size_t)(bh32 + t0q) * 4096;
            const short* k1t = kw + (size_t)(bh32 + t0c1) * 4096;
            const short* v0t = vw + (size_t)(bh32 + t0q) * 4096;
            async16(k0t + (size_t)(cb0 + lane) * 8, &kB[t0q % 3][cb0 * 8]);
            async16(k1t + (size_t)(cb0 + lane) * 8, &kB[(t0q + 1) % 3][cb0 * 8]);
            async16(v0t + (size_t)(cb0 + lane) * 8, &vB2[t0q & 1][cb0 * 8]);
        }

        // ---- convert Q (B-operand: Q[n=q=r16][k=e=quad*8+j]), scale*log2e folded
        const float qscale = 0.125f * LOG2E;
        bf16x8 qfrag[2][2];
        #pragma unroll
        for (int g = 0; g < 2; ++g) {
            #pragma unroll
            for (int es = 0; es < 2; ++es) {
                float4 a = qraw[g][es][0];
                float4 c = qraw[g][es][1];
                bf16x8 f;
                f[0] = f2bf(a.x * qscale); f[1] = f2bf(a.y * qscale);
                f[2] = f2bf(a.z * qscale); f[3] = f2bf(a.w * qscale);
                f[4] = f2bf(c.x * qscale); f[5] = f2bf(c.y * qscale);
                f[6] = f2bf(c.z * qscale); f[7] = f2bf(c.w * qscale);
                qfrag[g][es] = f;
            }
        }

        const float slope2 = __builtin_amdgcn_exp2f(-8.0f * (float)(h + 1) / (float)NH) * LOG2E;
        const float c64 = slope2 * 64.0f;
        // EA[g][r] = slope2*(key - q_g) - M_FIX, key = t0q*64 + kq*16 + quad*4 + r
        f32x4 EA[2];
        #pragma unroll
        for (int g = 0; g < 2; ++g)
            #pragma unroll
            for (int r = 0; r < 4; ++r)
                EA[g][r] = slope2 * (float)(t0q * 64 + kq * 16 + quad * 4 + r
                                            - (q0 + g * 16)) - M_FIX;

        f32x4 O[2][4] = {};   // O^T per group (partial over this wave's 16 keys)
        float rs[2] = {0.f, 0.f};

        for (int kt = t0q; kt <= t1; ++kt) {
            const int kc = kt % 3;
            const int vc = kt & 1;

            // sync 1: K(kt) landed (FIFO: only {K kt+1, V kt} newer)
            SYNC_VMCNT2();

            // prefetch K(kt+2), V(kt+1) — clamped at tail (uniform vmcnt issue)
            {
                const int kpre = (kt + 2 <= t1) ? kt + 2 : t1;
                const int vpre = (kt + 1 <= t1) ? kt + 1 : t1;
                const short* ktile = kw + (size_t)(bh32 + kpre) * 4096;
                const short* vtile = vw + (size_t)(bh32 + vpre) * 4096;
                async16(ktile + (size_t)(cb0 + lane) * 8, &kB[(kt + 2) % 3][cb0 * 8]);
                async16(vtile + (size_t)(cb0 + lane) * 8, &vB2[(kt + 1) & 1][cb0 * 8]);
            }

            // S^T = K Q^T for this wave's 16 keys, C-seeded with bias (EA).
            // K fragments read ONCE, used by both q-groups.
            f32x4 S[2];
            __builtin_amdgcn_s_setprio(1);
            {
                const int c0 = ((kq * 16 + r16) << 3) + swz;
                bf16x8 k0 = *(const bf16x8*)&kB[kc][c0 * 8];        // e in [quad*8,+8)
                bf16x8 k1 = *(const bf16x8*)&kB[kc][(c0 ^ 4) * 8];  // e in [32+quad*8,+8)
                #pragma unroll
                for (int g = 0; g < 2; ++g) {
                    f32x4 acc = __builtin_amdgcn_mfma_f32_16x16x32_bf16(k0, qfrag[g][0], EA[g], 0, 0, 0);
                    S[g] = __builtin_amdgcn_mfma_f32_16x16x32_bf16(k1, qfrag[g][1], acc, 0, 0, 0);
                }
            }
            __builtin_amdgcn_s_setprio(0);

            // p = exp2(S); already biased. Lands directly in PV B-fragment layout.
            bf16x4 pb[2];
            if (kt != t0q && kt != t1) {          // middle tiles: no mask possible
                #pragma unroll
                for (int g = 0; g < 2; ++g)
                    #pragma unroll
                    for (int r = 0; r < 4; ++r) {
                        const float pe = __builtin_amdgcn_exp2f(S[g][r]);
                        rs[g] += pe;
                        pb[g][r] = f2bf_trunc(pe);
                    }
            } else {                               // first tile / diagonal
                const int key0 = kt * 64 + kq * 16 + quad * 4;
                #pragma unroll
                for (int g = 0; g < 2; ++g) {
                    const int qg = q0 + g * 16;
                    #pragma unroll
                    for (int r = 0; r < 4; ++r) {
                        const int dist = qg - (key0 + r);
                        float pe = __builtin_amdgcn_exp2f(S[g][r]);
                        pe = (dist < 0 || dist >= WINDOW) ? 0.0f : pe;
                        rs[g] += pe;
                        pb[g][r] = f2bf_trunc(pe);
                    }
                }
            }

            // sync 2: V(kt) landed (FIFO: only {K kt+2, V kt+1} newer)
            SYNC_VMCNT2();

            // O^T += V^T P^T for this wave's 16 keys (b128 read, half used —
            // conflict-free; the b64 alternative is 8-way bank-conflicted).
            __builtin_amdgcn_s_setprio(1);
            {
                const int va = kq >> 1, vh = kq & 1;
                #pragma unroll
                for (int et = 0; et < 4; ++et) {
                    bf16x8 v8 = *(const bf16x8*)&vB2[vc][(size_t)((et * 2 + va) * 64 + lane) * 8];
                    bf16x4 vf;
                    if (vh == 0) { vf[0] = v8[0]; vf[1] = v8[1]; vf[2] = v8[2]; vf[3] = v8[3]; }
                    else         { vf[0] = v8[4]; vf[1] = v8[5]; vf[2] = v8[6]; vf[3] = v8[7]; }
                    O[0][et] = mfma16(vf, pb[0], O[0][et]);
                    O[1][et] = mfma16(vf, pb[1], O[1][et]);
                }
            }
            __builtin_amdgcn_s_setprio(0);

            EA[0] += c64;
            EA[1] += c64;
        }

        // ---- combine the 4 kq partials (exact: fixed-max -> partials add) ----
        __syncthreads();                       // full drain (incl. tail DMAs)
        float* sc = (float*)&smem[0];          // 8192 floats O-scratch
        float* rc = sc + 8192;                 // 512 floats rs-scratch
        if (kq >= 2) {                         // step (a): kq 2,3 publish
            const int base = (qhalf * 2 + (kq - 2)) * 2;
            #pragma unroll
            for (int g = 0; g < 2; ++g)
                #pragma unroll
                for (int et = 0; et < 4; ++et)
                    #pragma unroll
                    for (int j = 0; j < 4; ++j)
                        sc[(((base + g) * 4 + et) * 4 + j) * 64 + lane] = O[g][et][j];
            rc[(base + 0) * 64 + lane] = rs[0];
            rc[(base + 1) * 64 + lane] = rs[1];
        }
        __syncthreads();
        if (kq < 2) {                          // kq 0,1 absorb partner kq+2
            const int base = (qhalf * 2 + kq) * 2;
            #pragma unroll
            for (int g = 0; g < 2; ++g)
                #pragma unroll
                for (int et = 0; et < 4; ++et)
                    #pragma unroll
                    for (int j = 0; j < 4; ++j)
                        O[g][et][j] += sc[(((base + g) * 4 + et) * 4 + j) * 64 + lane];
            rs[0] += rc[(base + 0) * 64 + lane];
            rs[1] += rc[(base + 1) * 64 + lane];
        }
        __syncthreads();
        if (kq == 1) {                         // step (b): kq 1 publishes
            const int base = qhalf * 2;
            #pragma unroll
            for (int g = 0; g < 2; ++g)
                #pragma unroll
                for (int et = 0; et < 4; ++et)
                    #pragma unroll
                    for (int j = 0; j < 4; ++j)
                        sc[(((base + g) * 4 + et) * 4 + j) * 64 + lane] = O[g][et][j];
            rc[(base + 0) * 64 + lane] = rs[0];
            rc[(base + 1) * 64 + lane] = rs[1];
        }
        __syncthreads();
        if (kq == 0) {                         // step (c): kq 0 finalizes + stores
            const int base = qhalf * 2;
            #pragma unroll
            for (int g = 0; g < 2; ++g) {
                #pragma unroll
                for (int et = 0; et < 4; ++et)
                    #pragma unroll
                    for (int j = 0; j < 4; ++j)
                        O[g][et][j] += sc[(((base + g) * 4 + et) * 4 + j) * 64 + lane];
                float r = rs[g] + rc[(base + g) * 64 + lane];
                r += __shfl_xor(r, 16, 64);
                r += __shfl_xor(r, 32, 64);
                const float rl = 1.0f / r;
                float* op = out + ((size_t)b * L_SEQ + (q0 + g * 16)) * (NH * EDIM) + h * EDIM;
                #pragma unroll
                for (int et = 0; et < 4; ++et) {
                    float4 o4 = {O[g][et][0] * rl, O[g][et][1] * rl,
                                 O[g][et][2] * rl, O[g][et][3] * rl};
                    *(float4*)(op + et * 16 + quad * 4) = o4;
                }
            }
        }
        // next item's writes are ordered behind the loop-top __syncthreads()
    }
}

// ---------------- fallback (no workspace): round-1 style, fp32 in-kernel staging ----------------
__global__ __launch_bounds__(256, 2) void flexattn_fwd_fb(
        const float* __restrict__ qkv, float* __restrict__ out) {
    __shared__ __align__(16) short kT[KT * 72];
    __shared__ __align__(16) short vB[8 * 64 * 8];
    __shared__ __align__(16) short pT[4][16 * 72];

    const int qtile = blockIdx.x;
    const int h     = blockIdx.y;
    const int b     = blockIdx.z;
    const int tid   = threadIdx.x;
    const int w     = tid >> 6;
    const int lane  = tid & 63;
    const int quad  = lane >> 4;
    const int r16   = lane & 15;
    const int qb = qtile * QT;
    const int rowstride = 3 * NH * EDIM;

    const float* qbase = qkv + ((size_t)b * L_SEQ * 3 + 0) * (NH * EDIM) + h * EDIM;
    const float* kbase = qkv + ((size_t)b * L_SEQ * 3 + 1) * (NH * EDIM) + h * EDIM;
    const float* vbase = qkv + ((size_t)b * L_SEQ * 3 + 2) * (NH * EDIM) + h * EDIM;

    const float qscale = 0.125f * LOG2E;
    bf16x8 qfrag[2];
    {
        const int qg = qb + w * 16 + r16;
        const float* qrow = qbase + (size_t)qg * rowstride;
        #pragma unroll
        for (int es = 0; es < 2; ++es) {
            const float* p = qrow + es * 32 + quad * 8;
            float4 a = *(const float4*)p;
            float4 c = *(const float4*)(p + 4);
            bf16x8 f;
            f[0] = f2bf(a.x * qscale); f[1] = f2bf(a.y * qscale);
            f[2] = f2bf(a.z * qscale); f[3] = f2bf(a.w * qscale);
            f[4] = f2bf(c.x * qscale); f[5] = f2bf(c.y * qscale);
            f[6] = f2bf(c.z * qscale); f[7] = f2bf(c.w * qscale);
            qfrag[es] = f;
        }
    }

    const float slope2 = __builtin_amdgcn_exp2f(-8.0f * (float)(h + 1) / (float)NH) * LOG2E;
    f32x4 O[4] = {{0,0,0,0},{0,0,0,0},{0,0,0,0},{0,0,0,0}};
    float m_run[4] = {-1e30f, -1e30f, -1e30f, -1e30f};
    float l_run[4] = {0.f, 0.f, 0.f, 0.f};

    const int kmin = (qb >= WINDOW - 1) ? (qb - (WINDOW - 1)) : 0;
    const int t0 = kmin >> 6;
    const int t1 = qtile;

    for (int kt = t0; kt <= t1; ++kt) {
        __syncthreads();
        {
            const int j = tid >> 2;
            const int ebase = (tid & 3) * 16;
            const float* krow = kbase + (size_t)(kt * KT + j) * rowstride + ebase;
            const float* vrow = vbase + (size_t)(kt * KT + j) * rowstride + ebase;
            const int js = j >> 5, qd = (j >> 3) & 3, ii = j & 7;
            #pragma unroll
            for (int ee = 0; ee < 4; ++ee) {
                const int e = ebase + ee * 4;
                float4 k4 = *(const float4*)(krow + ee * 4);
                short* kd = &kT[j * 72 + e];
                kd[0] = f2bf(k4.x); kd[1] = f2bf(k4.y);
                kd[2] = f2bf(k4.z); kd[3] = f2bf(k4.w);
                float4 v4 = *(const float4*)(vrow + ee * 4);
                const int et = e >> 4;
                const int ln = qd * 16 + (e & 15);
                short* vd = &vB[(((js * 4 + et) * 64) + ln) * 8 + ii];
                vd[0]  = f2bf(v4.x);
                vd[8]  = f2bf(v4.y);
                vd[16] = f2bf(v4.z);
                vd[24] = f2bf(v4.w);
            }
        }
        __syncthreads();

        f32x4 S[4];
        #pragma unroll
        for (int ct = 0; ct < 4; ++ct) {
            const short* kr = &kT[(ct * 16 + r16) * 72 + quad * 8];
            bf16x8 b0 = *(const bf16x8*)kr;
            bf16x8 b1 = *(const bf16x8*)(kr + 32);
            f32x4 acc = {0.f, 0.f, 0.f, 0.f};
            acc = __builtin_amdgcn_mfma_f32_16x16x32_bf16(qfrag[0], b0, acc, 0, 0, 0);
            acc = __builtin_amdgcn_mfma_f32_16x16x32_bf16(qfrag[1], b1, acc, 0, 0, 0);
            S[ct] = acc;
        }

        const int q0 = qb + w * 16 + quad * 4;
        float p[4][4];
        float mt[4] = {-1e30f, -1e30f, -1e30f, -1e30f};
        #pragma unroll
        for (int ct = 0; ct < 4; ++ct) {
            const int kg = kt * KT + ct * 16 + r16;
            #pragma unroll
            for (int r = 0; r < 4; ++r) {
                const int dist = q0 + r - kg;
                float s2 = S[ct][r] - slope2 * (float)dist;
                if (dist < 0 || dist >= WINDOW) s2 = -1e30f;
                p[ct][r] = s2;
                mt[r] = fmaxf(mt[r], s2);
            }
        }
        #pragma unroll
        for (int d = 1; d < 16; d <<= 1) {
            #pragma unroll
            for (int r = 0; r < 4; ++r)
                mt[r] = fmaxf(mt[r], __shfl_xor(mt[r], d, 64));
        }

        float alpha[4], rsum[4];
        #pragma unroll
        for (int r = 0; r < 4; ++r) {
            const float mn = fmaxf(m_run[r], mt[r]);
            alpha[r] = __builtin_amdgcn_exp2f(m_run[r] - mn);
            m_run[r] = mn;
            float sacc = 0.f;
            #pragma unroll
            for (int ct = 0; ct < 4; ++ct) {
                const float pe = __builtin_amdgcn_exp2f(p[ct][r] - mn);
                p[ct][r] = pe;
                sacc += pe;
            }
            rsum[r] = sacc;
        }
        #pragma unroll
        for (int d = 1; d < 16; d <<= 1) {
            #pragma unroll
            for (int r = 0; r < 4; ++r)
                rsum[r] += __shfl_xor(rsum[r], d, 64);
        }
        #pragma unroll
        for (int r = 0; r < 4; ++r)
            l_run[r] = l_run[r] * alpha[r] + rsum[r];
        #pragma unroll
        for (int et = 0; et < 4; ++et) {
            #pragma unroll
            for (int r = 0; r < 4; ++r)
                O[et][r] *= alpha[r];
        }

        short* pw = &pT[w][0];
        #pragma unroll
        for (int ct = 0; ct < 4; ++ct) {
            #pragma unroll
            for (int r = 0; r < 4; ++r)
                pw[(quad * 4 + r) * 72 + ct * 16 + r16] = f2bf(p[ct][r]);
        }
        bf16x8 aP0 = *(const bf16x8*)(pw + r16 * 72 + quad * 8);
        bf16x8 aP1 = *(const bf16x8*)(pw + r16 * 72 + 32 + quad * 8);

        #pragma unroll
        for (int et = 0; et < 4; ++et) {
            bf16x8 v0 = *(const bf16x8*)(&vB[((0 * 4 + et) * 64 + lane) * 8]);
            O[et] = __builtin_amdgcn_mfma_f32_16x16x32_bf16(aP0, v0, O[et], 0, 0, 0);
            bf16x8 v1 = *(const bf16x8*)(&vB[((1 * 4 + et) * 64 + lane) * 8]);
            O[et] = __builtin_amdgcn_mfma_f32_16x16x32_bf16(aP1, v1, O[et], 0, 0, 0);
        }
    }

    float* obase = out + (((size_t)b * L_SEQ) * NH + (size_t)h) * EDIM;
    #pragma unroll
    for (int r = 0; r < 4; ++r) {
        const int qg = qb + w * 16 + quad * 4 + r;
        const float rl = 1.0f / l_run[r];
        float* orow = obase + (size_t)qg * (NH * EDIM);
        #pragma unroll
        for (int et = 0; et < 4; ++et)
            orow[et * 16 + r16] = O[et][r] * rl;
    }
}

extern "C" void kernel_launch(void* const* d_in, const int* in_sizes, int n_in,
                              void* d_out, int out_size, void* d_ws, size_t ws_size,
                              hipStream_t stream) {
    const float* qkv = (const float*)d_in[0];
    float* out = (float*)d_out;
    const size_t kv_elems = (size_t)1024 * 4096;
    const size_t need = 2 * kv_elems * sizeof(short) + 8 * sizeof(int);
    if (ws_size >= need) {
        short* kw = (short*)d_ws;
        short* vw = kw + kv_elems;
        int* cnt = (int*)(vw + kv_elems);
        prepass5<<<1024, 256, 0, stream>>>(qkv, kw, vw, cnt);
        dim3 grid(8, 64);
        flexattn_fwd10<<<grid, 512, 0, stream>>>(qkv, kw, vw, cnt, out);
    } else {
        dim3 gridfb(L_SEQ / QT, NH, 2);
        flexattn_fwd_fb<<<gridfb, 256, 0, stream>>>(qkv, out);
    }
}

// Round 7
// 117.116 us; speedup vs baseline: 1.0786x; 1.0786x over previous
//
#include <hip/hip_runtime.h>
#include <cstdint>

#define L_SEQ 2048
#define NH 16
#define EDIM 64
#define WINDOW 1024
#define QT 64
#define KT 64
#define LOG2E 1.4426950408889634f
#define M_FIX 16.0f   // fixed softmax max in log2 domain (scores bounded ~|10|)

typedef short bf16x8 __attribute__((ext_vector_type(8)));
typedef short bf16x4 __attribute__((ext_vector_type(4)));
typedef float f32x4 __attribute__((ext_vector_type(4)));

__device__ __forceinline__ short f2bf(float x) {   // RNE
    uint32_t u = __builtin_bit_cast(uint32_t, x);
    uint32_t r = (u + 0x7fffu + ((u >> 16) & 1u)) >> 16;
    return (short)(r & 0xffffu);
}
__device__ __forceinline__ short f2bf_trunc(float x) {
    return (short)(__builtin_bit_cast(uint32_t, x) >> 16);
}

// 16x16x16 bf16 MFMA: builtin when the toolchain has it, else raw asm
__device__ __forceinline__ f32x4 mfma16(bf16x4 a, bf16x4 b, f32x4 c) {
#if __has_builtin(__builtin_amdgcn_mfma_f32_16x16x16bf16_1k)
    return __builtin_amdgcn_mfma_f32_16x16x16bf16_1k(a, b, c, 0, 0, 0);
#else
    asm("s_nop 1\n\tv_mfma_f32_16x16x16_bf16 %0, %1, %2, %0"
        : "+v"(c) : "v"(a), "v"(b));
    return c;
#endif
}

// ---------------- prepass (UNCHANGED from v5/v7/v8 — HW-verified) ----------------
//  XCD-local to consumer: attn waves on XCD x read pairs 4x..4x+3.
//  K chunk c : row=c>>3, cc=(c&7)^(row&7) : K[row][cc*8 + j]   (XOR swizzle)
//  V chunk c = et*128 + a*64 + quad*16 + r16 :
//      j 0..3 -> V[a*32 + quad*4 + j][et*16 + r16]
//      j 4..7 -> V[a*32 + 16 + quad*4 + (j-4)][et*16 + r16]
__global__ __launch_bounds__(256) void prepass4(const float* __restrict__ qkv,
        short* __restrict__ kw, short* __restrict__ vw) {
    __shared__ float vt[64][68];   // vt[e][row]; 272 B rows -> 16B-aligned float4
    const int x = blockIdx.x;      // 1024 blocks
    const int xcd = x & 7, y = x >> 3;
    const int pairid = xcd * 4 + (y >> 5);   // pairs 4x..4x+3 on XCD x
    const int tile = y & 31;
    const int b = pairid >> 4, h = pairid & 15;
    const int tid = threadIdx.x;
    const int tg = pairid * 32 + tile;
    const float* base = qkv + (size_t)b * (L_SEQ * 3072) + (size_t)tile * 64 * 3072 + h * 64;
    short* ko = kw + (size_t)tg * 4096;
    short* vo = vw + (size_t)tg * 4096;

    // K (XOR-swizzled chunk order)
    #pragma unroll
    for (int it = 0; it < 2; ++it) {
        const int c = tid + it * 256;
        const int row = c >> 3, cc = (c & 7) ^ (row & 7);
        const float* src = base + (size_t)row * 3072 + 1024 + cc * 8;
        float4 a = *(const float4*)src, d = *(const float4*)(src + 4);
        short* o = ko + (size_t)c * 8;
        o[0] = f2bf(a.x); o[1] = f2bf(a.y); o[2] = f2bf(a.z); o[3] = f2bf(a.w);
        o[4] = f2bf(d.x); o[5] = f2bf(d.y); o[6] = f2bf(d.z); o[7] = f2bf(d.w);
    }
    // V: coalesced row reads -> transposed LDS
    {
        const int row = tid >> 2, e0 = (tid & 3) << 4;
        const float* src = base + (size_t)row * 3072 + 2048 + e0;
        #pragma unroll
        for (int q4 = 0; q4 < 4; ++q4) {
            float4 a = *(const float4*)(src + q4 * 4);
            vt[e0 + q4 * 4 + 0][row] = a.x;
            vt[e0 + q4 * 4 + 1][row] = a.y;
            vt[e0 + q4 * 4 + 2][row] = a.z;
            vt[e0 + q4 * 4 + 3][row] = a.w;
        }
    }
    __syncthreads();
    #pragma unroll
    for (int it = 0; it < 2; ++it) {
        const int c = tid + it * 256;
        const int et = c >> 7, a = (c >> 6) & 1, l6 = c & 63;
        const int quad = l6 >> 4, r16 = l6 & 15;
        const int e = et * 16 + r16;
        float4 x0 = *(const float4*)&vt[e][a * 32 + quad * 4];
        float4 x1 = *(const float4*)&vt[e][a * 32 + 16 + quad * 4];
        bf16x8 o8;
        o8[0] = f2bf(x0.x); o8[1] = f2bf(x0.y); o8[2] = f2bf(x0.z); o8[3] = f2bf(x0.w);
        o8[4] = f2bf(x1.x); o8[5] = f2bf(x1.y); o8[6] = f2bf(x1.z); o8[7] = f2bf(x1.w);
        *(bf16x8*)(vo + (size_t)c * 8) = o8;
    }
}

// ---------------- attention v12: static zero-barrier waveflash ----------------
// Diagnosis across v5..v10: MFMA busy ~7us + VALU busy ~12us but attn 38-44us
// -> ~25us of ALL-wave simultaneous stall = per-tile barrier convoying. v12
// removes all synchronization: one wave per 64-thr block, one static item
// (pair, qhalf=32q, qtile) per wave, K/V straight from XCD-local L2.
// Data path is byte-identical to the HW-verified v5 kernel: same prepass4
// workspace, same K chunk formula c0=((ct*16+r16)<<3)+swz (LDS read -> global
// read of the same bytes), same V chunks (et*2+a)*64+lane, v7/v8-verified EA
// C-seed bias with incremental advance, v5 epilogue.
// Static balance: block l -> XCD l&7 (pairs 4x..4x+3, L2-local); with CU =
// (l/8)%32 round-robin, each CU's 8 resident waves get qtiles forming two
// {s,15-s,16+s,31-s} quads = exactly 102 tile-units per CU.
__global__ __launch_bounds__(64, 2) void flexattn_fwd12(
        const float* __restrict__ qkv, const short* __restrict__ kw,
        const short* __restrict__ vw, float* __restrict__ out) {
    const int l    = blockIdx.x;     // 0..2047
    const int lane = threadIdx.x;    // 0..63 (one wave)
    const int quad = lane >> 4;
    const int r16  = lane & 15;
    const int swz  = quad ^ (r16 & 7);

    // item decode: l -> (pair, qhalf, qtile); bijective, CU-balanced
    const int pairid = (l & 7) * 4 + ((l >> 3) & 3);
    const int qhalf  = (l >> 5) & 1;
    const int u      = l >> 6;            // 0..31
    const int v      = u & 3;             // fixed per CU slot
    const int m      = u >> 2;            // 0..7 across a CU's 8 waves
    const int s      = v + ((m >> 2) << 2);          // v or v+4
    const int j      = m & 3;
    const int qtile  = (j == 0) ? (31 - s) : (j == 1) ? (16 + s)
                     : (j == 2) ? (15 - s) : s;      // {17,17,16-s,s+1} quads

    const int h  = pairid & 15;
    const int b  = pairid >> 4;
    const int qb = qtile * QT;
    const int bh32 = pairid * 32;
    const int q0 = qb + qhalf * 32 + r16;            // group-0 query; group-1 = +16
    const int t0q = (qb >= WINDOW - 1) ? ((qb - (WINDOW - 1)) >> 6) : 0;
    const int t1  = qtile;

    // ---- Q load + convert (v5-identical; B-operand Q[n=q=r16][k=e=quad*8+j])
    const float qscale = 0.125f * LOG2E;
    bf16x8 qfrag[2][2];
    #pragma unroll
    for (int g = 0; g < 2; ++g) {
        const float* qrow = qkv + (size_t)b * (L_SEQ * 3072)
                                + (size_t)(q0 + g * 16) * 3072 + h * 64;
        #pragma unroll
        for (int es = 0; es < 2; ++es) {
            const float* p = qrow + es * 32 + quad * 8;
            float4 a = *(const float4*)p;
            float4 c = *(const float4*)(p + 4);
            bf16x8 f;
            f[0] = f2bf(a.x * qscale); f[1] = f2bf(a.y * qscale);
            f[2] = f2bf(a.z * qscale); f[3] = f2bf(a.w * qscale);
            f[4] = f2bf(c.x * qscale); f[5] = f2bf(c.y * qscale);
            f[6] = f2bf(c.z * qscale); f[7] = f2bf(c.w * qscale);
            qfrag[g][es] = f;
        }
    }

    const float slope2 = __builtin_amdgcn_exp2f(-8.0f * (float)(h + 1) / (float)NH) * LOG2E;
    const float c64 = slope2 * 64.0f;
    // EA[g][ct][r] = slope2*(key - q_g) - M_FIX, key = t0q*64 + ct*16 + quad*4 + r
    // (v7/v8-verified form, incl. the += c64 per-tile advance)
    f32x4 EA[2][4];
    #pragma unroll
    for (int g = 0; g < 2; ++g)
        #pragma unroll
        for (int ct = 0; ct < 4; ++ct)
            #pragma unroll
            for (int r = 0; r < 4; ++r)
                EA[g][ct][r] = slope2 * (float)(t0q * 64 + ct * 16 + quad * 4 + r
                                                - (q0 + g * 16)) - M_FIX;

    f32x4 O[2][4] = {};
    float rs[2] = {0.f, 0.f};

// K fragment loads: EXACT v5 chunk selection (c0, c0^4), global instead of LDS
#define KLOAD12(DST, TKT) do {                                            \
        const short* _kp = kw + (size_t)(bh32 + (TKT)) * 4096;            \
        _Pragma("unroll")                                                 \
        for (int _ct = 0; _ct < 4; ++_ct) {                               \
            const int _c0 = ((_ct * 16 + r16) << 3) + swz;                \
            DST[_ct * 2 + 0] = *(const bf16x8*)(_kp + (size_t)_c0 * 8);   \
            DST[_ct * 2 + 1] = *(const bf16x8*)(_kp + (size_t)(_c0 ^ 4) * 8); \
        }                                                                 \
    } while (0)

#define TILE12(CUR, NXT) do {                                             \
        bf16x8 vr[8];                                                     \
        {   const short* _vp = vw + (size_t)(bh32 + kt) * 4096;           \
            _Pragma("unroll")                                             \
            for (int _i = 0; _i < 8; ++_i)                                \
                vr[_i] = *(const bf16x8*)(_vp + (size_t)(_i * 64 + lane) * 8); } \
        if (kt < t1) KLOAD12(NXT, kt + 1);                                \
        f32x4 S[2][4];                                                    \
        __builtin_amdgcn_s_setprio(1);                                    \
        _Pragma("unroll")                                                 \
        for (int ct = 0; ct < 4; ++ct) {                                  \
            _Pragma("unroll")                                             \
            for (int g = 0; g < 2; ++g) {                                 \
                f32x4 acc = __builtin_amdgcn_mfma_f32_16x16x32_bf16(      \
                    CUR[ct * 2 + 0], qfrag[g][0], EA[g][ct], 0, 0, 0);    \
                S[g][ct] = __builtin_amdgcn_mfma_f32_16x16x32_bf16(       \
                    CUR[ct * 2 + 1], qfrag[g][1], acc, 0, 0, 0);          \
            }                                                             \
        }                                                                 \
        __builtin_amdgcn_s_setprio(0);                                    \
        bf16x4 pb[2][4];                                                  \
        if (kt != t0q && kt != t1) {   /* middle: no mask possible */     \
            _Pragma("unroll")                                             \
            for (int g = 0; g < 2; ++g)                                   \
                _Pragma("unroll")                                         \
                for (int ct = 0; ct < 4; ++ct)                            \
                    _Pragma("unroll")                                     \
                    for (int r = 0; r < 4; ++r) {                         \
                        const float pe = __builtin_amdgcn_exp2f(S[g][ct][r]); \
                        rs[g] += pe;                                      \
                        pb[g][ct][r] = f2bf_trunc(pe);                    \
                    }                                                     \
        } else {                       /* first (dist>=W) / diagonal */   \
            const int key0 = kt * 64 + quad * 4;                          \
            _Pragma("unroll")                                             \
            for (int g = 0; g < 2; ++g) {                                 \
                const int qg = q0 + g * 16;                               \
                _Pragma("unroll")                                         \
                for (int ct = 0; ct < 4; ++ct)                            \
                    _Pragma("unroll")                                     \
                    for (int r = 0; r < 4; ++r) {                         \
                        const int dist = qg - (key0 + ct * 16 + r);       \
                        float pe = __builtin_amdgcn_exp2f(S[g][ct][r]);   \
                        pe = (dist < 0 || dist >= WINDOW) ? 0.0f : pe;    \
                        rs[g] += pe;                                      \
                        pb[g][ct][r] = f2bf_trunc(pe);                    \
                    }                                                     \
            }                                                             \
        }                                                                 \
        __builtin_amdgcn_s_setprio(1);                                    \
        _Pragma("unroll")                                                 \
        for (int et = 0; et < 4; ++et) {                                  \
            _Pragma("unroll")                                             \
            for (int a = 0; a < 2; ++a) {                                 \
                bf16x8 v8 = vr[et * 2 + a];                               \
                bf16x4 vlo = {v8[0], v8[1], v8[2], v8[3]};                \
                bf16x4 vhi = {v8[4], v8[5], v8[6], v8[7]};                \
                _Pragma("unroll")                                         \
                for (int g = 0; g < 2; ++g) {                             \
                    O[g][et] = mfma16(vlo, pb[g][a * 2 + 0], O[g][et]);   \
                    O[g][et] = mfma16(vhi, pb[g][a * 2 + 1], O[g][et]);   \
                }                                                         \
            }                                                             \
        }                                                                 \
        __builtin_amdgcn_s_setprio(0);                                    \
        _Pragma("unroll")                                                 \
        for (int ct = 0; ct < 4; ++ct) { EA[0][ct] += c64; EA[1][ct] += c64; } \
    } while (0)

    bf16x8 KA[8], KB[8];
    KLOAD12(KA, t0q);
    int kt = t0q;
    for (;;) {
        TILE12(KA, KB);
        if (kt == t1) break;
        ++kt;
        TILE12(KB, KA);
        if (kt == t1) break;
        ++kt;
    }
#undef TILE12
#undef KLOAD12

    // ---- epilogue (v5-identical): lanes {quad 0..3} x same r16 share q
    #pragma unroll
    for (int g = 0; g < 2; ++g) {
        float r = rs[g];
        r += __shfl_xor(r, 16, 64);
        r += __shfl_xor(r, 32, 64);
        const float rl = 1.0f / r;
        float* op = out + ((size_t)b * L_SEQ + (q0 + g * 16)) * (NH * EDIM) + h * EDIM;
        #pragma unroll
        for (int et = 0; et < 4; ++et) {
            float4 o4 = {O[g][et][0] * rl, O[g][et][1] * rl,
                         O[g][et][2] * rl, O[g][et][3] * rl};
            *(float4*)(op + et * 16 + quad * 4) = o4;
        }
    }
}

// ---------------- fallback (no workspace): round-1 style, fp32 in-kernel staging ----------------
__global__ __launch_bounds__(256, 2) void flexattn_fwd_fb(
        const float* __restrict__ qkv, float* __restrict__ out) {
    __shared__ __align__(16) short kT[KT * 72];
    __shared__ __align__(16) short vB[8 * 64 * 8];
    __shared__ __align__(16) short pT[4][16 * 72];

    const int qtile = blockIdx.x;
    const int h     = blockIdx.y;
    const int b     = blockIdx.z;
    const int tid   = threadIdx.x;
    const int w     = tid >> 6;
    const int lane  = tid & 63;
    const int quad  = lane >> 4;
    const int r16   = lane & 15;
    const int qb = qtile * QT;
    const int rowstride = 3 * NH * EDIM;

    const float* qbase = qkv + ((size_t)b * L_SEQ * 3 + 0) * (NH * EDIM) + h * EDIM;
    const float* kbase = qkv + ((size_t)b * L_SEQ * 3 + 1) * (NH * EDIM) + h * EDIM;
    const float* vbase = qkv + ((size_t)b * L_SEQ * 3 + 2) * (NH * EDIM) + h * EDIM;

    const float qscale = 0.125f * LOG2E;
    bf16x8 qfrag[2];
    {
        const int qg = qb + w * 16 + r16;
        const float* qrow = qbase + (size_t)qg * rowstride;
        #pragma unroll
        for (int es = 0; es < 2; ++es) {
            const float* p = qrow + es * 32 + quad * 8;
            float4 a = *(const float4*)p;
            float4 c = *(const float4*)(p + 4);
            bf16x8 f;
            f[0] = f2bf(a.x * qscale); f[1] = f2bf(a.y * qscale);
            f[2] = f2bf(a.z * qscale); f[3] = f2bf(a.w * qscale);
            f[4] = f2bf(c.x * qscale); f[5] = f2bf(c.y * qscale);
            f[6] = f2bf(c.z * qscale); f[7] = f2bf(c.w * qscale);
            qfrag[es] = f;
        }
    }

    const float slope2 = __builtin_amdgcn_exp2f(-8.0f * (float)(h + 1) / (float)NH) * LOG2E;
    f32x4 O[4] = {{0,0,0,0},{0,0,0,0},{0,0,0,0},{0,0,0,0}};
    float m_run[4] = {-1e30f, -1e30f, -1e30f, -1e30f};
    float l_run[4] = {0.f, 0.f, 0.f, 0.f};

    const int kmin = (qb >= WINDOW - 1) ? (qb - (WINDOW - 1)) : 0;
    const int t0 = kmin >> 6;
    const int t1 = qtile;

    for (int kt = t0; kt <= t1; ++kt) {
        __syncthreads();
        {
            const int j = tid >> 2;
            const int ebase = (tid & 3) * 16;
            const float* krow = kbase + (size_t)(kt * KT + j) * rowstride + ebase;
            const float* vrow = vbase + (size_t)(kt * KT + j) * rowstride + ebase;
            const int js = j >> 5, qd = (j >> 3) & 3, ii = j & 7;
            #pragma unroll
            for (int ee = 0; ee < 4; ++ee) {
                const int e = ebase + ee * 4;
                float4 k4 = *(const float4*)(krow + ee * 4);
                short* kd = &kT[j * 72 + e];
                kd[0] = f2bf(k4.x); kd[1] = f2bf(k4.y);
                kd[2] = f2bf(k4.z); kd[3] = f2bf(k4.w);
                float4 v4 = *(const float4*)(vrow + ee * 4);
                const int et = e >> 4;
                const int ln = qd * 16 + (e & 15);
                short* vd = &vB[(((js * 4 + et) * 64) + ln) * 8 + ii];
                vd[0]  = f2bf(v4.x);
                vd[8]  = f2bf(v4.y);
                vd[16] = f2bf(v4.z);
                vd[24] = f2bf(v4.w);
            }
        }
        __syncthreads();

        f32x4 S[4];
        #pragma unroll
        for (int ct = 0; ct < 4; ++ct) {
            const short* kr = &kT[(ct * 16 + r16) * 72 + quad * 8];
            bf16x8 b0 = *(const bf16x8*)kr;
            bf16x8 b1 = *(const bf16x8*)(kr + 32);
            f32x4 acc = {0.f, 0.f, 0.f, 0.f};
            acc = __builtin_amdgcn_mfma_f32_16x16x32_bf16(qfrag[0], b0, acc, 0, 0, 0);
            acc = __builtin_amdgcn_mfma_f32_16x16x32_bf16(qfrag[1], b1, acc, 0, 0, 0);
            S[ct] = acc;
        }

        const int q0 = qb + w * 16 + quad * 4;
        float p[4][4];
        float mt[4] = {-1e30f, -1e30f, -1e30f, -1e30f};
        #pragma unroll
        for (int ct = 0; ct < 4; ++ct) {
            const int kg = kt * KT + ct * 16 + r16;
            #pragma unroll
            for (int r = 0; r < 4; ++r) {
                const int dist = q0 + r - kg;
                float s2 = S[ct][r] - slope2 * (float)dist;
                if (dist < 0 || dist >= WINDOW) s2 = -1e30f;
                p[ct][r] = s2;
                mt[r] = fmaxf(mt[r], s2);
            }
        }
        #pragma unroll
        for (int d = 1; d < 16; d <<= 1) {
            #pragma unroll
            for (int r = 0; r < 4; ++r)
                mt[r] = fmaxf(mt[r], __shfl_xor(mt[r], d, 64));
        }

        float alpha[4], rsum[4];
        #pragma unroll
        for (int r = 0; r < 4; ++r) {
            const float mn = fmaxf(m_run[r], mt[r]);
            alpha[r] = __builtin_amdgcn_exp2f(m_run[r] - mn);
            m_run[r] = mn;
            float sacc = 0.f;
            #pragma unroll
            for (int ct = 0; ct < 4; ++ct) {
                const float pe = __builtin_amdgcn_exp2f(p[ct][r] - mn);
                p[ct][r] = pe;
                sacc += pe;
            }
            rsum[r] = sacc;
        }
        #pragma unroll
        for (int d = 1; d < 16; d <<= 1) {
            #pragma unroll
            for (int r = 0; r < 4; ++r)
                rsum[r] += __shfl_xor(rsum[r], d, 64);
        }
        #pragma unroll
        for (int r = 0; r < 4; ++r)
            l_run[r] = l_run[r] * alpha[r] + rsum[r];
        #pragma unroll
        for (int et = 0; et < 4; ++et) {
            #pragma unroll
            for (int r = 0; r < 4; ++r)
                O[et][r] *= alpha[r];
        }

        short* pw = &pT[w][0];
        #pragma unroll
        for (int ct = 0; ct < 4; ++ct) {
            #pragma unroll
            for (int r = 0; r < 4; ++r)
                pw[(quad * 4 + r) * 72 + ct * 16 + r16] = f2bf(p[ct][r]);
        }
        bf16x8 aP0 = *(const bf16x8*)(pw + r16 * 72 + quad * 8);
        bf16x8 aP1 = *(const bf16x8*)(pw + r16 * 72 + 32 + quad * 8);

        #pragma unroll
        for (int et = 0; et < 4; ++et) {
            bf16x8 v0 = *(const bf16x8*)(&vB[((0 * 4 + et) * 64 + lane) * 8]);
            O[et] = __builtin_amdgcn_mfma_f32_16x16x32_bf16(aP0, v0, O[et], 0, 0, 0);
            bf16x8 v1 = *(const bf16x8*)(&vB[((1 * 4 + et) * 64 + lane) * 8]);
            O[et] = __builtin_amdgcn_mfma_f32_16x16x32_bf16(aP1, v1, O[et], 0, 0, 0);
        }
    }

    float* obase = out + (((size_t)b * L_SEQ) * NH + (size_t)h) * EDIM;
    #pragma unroll
    for (int r = 0; r < 4; ++r) {
        const int qg = qb + w * 16 + quad * 4 + r;
        const float rl = 1.0f / l_run[r];
        float* orow = obase + (size_t)qg * (NH * EDIM);
        #pragma unroll
        for (int et = 0; et < 4; ++et)
            orow[et * 16 + r16] = O[et][r] * rl;
    }
}

extern "C" void kernel_launch(void* const* d_in, const int* in_sizes, int n_in,
                              void* d_out, int out_size, void* d_ws, size_t ws_size,
                              hipStream_t stream) {
    const float* qkv = (const float*)d_in[0];
    float* out = (float*)d_out;
    const size_t kv_elems = (size_t)1024 * 4096;
    const size_t need = 2 * kv_elems * sizeof(short);   // K + V, 16.8 MB
    if (ws_size >= need) {
        short* kw = (short*)d_ws;
        short* vw = kw + kv_elems;
        prepass4<<<1024, 256, 0, stream>>>(qkv, kw, vw);
        flexattn_fwd12<<<2048, 64, 0, stream>>>(qkv, kw, vw, out);
    } else {
        dim3 gridfb(L_SEQ / QT, NH, 2);
        flexattn_fwd_fb<<<gridfb, 256, 0, stream>>>(qkv, out);
    }
}

// Round 8
// 114.637 us; speedup vs baseline: 1.1019x; 1.0216x over previous
//
#include <hip/hip_runtime.h>
#include <cstdint>

#define L_SEQ 2048
#define NH 16
#define EDIM 64
#define WINDOW 1024
#define QT 64
#define KT 64
#define LOG2E 1.4426950408889634f
#define M_FIX 16.0f   // fixed softmax max in log2 domain (scores bounded ~|10|)

typedef short bf16x8 __attribute__((ext_vector_type(8)));
typedef short bf16x4 __attribute__((ext_vector_type(4)));
typedef float f32x4 __attribute__((ext_vector_type(4)));

__device__ __forceinline__ short f2bf(float x) {   // RNE
    uint32_t u = __builtin_bit_cast(uint32_t, x);
    uint32_t r = (u + 0x7fffu + ((u >> 16) & 1u)) >> 16;
    return (short)(r & 0xffffu);
}
__device__ __forceinline__ short f2bf_trunc(float x) {
    return (short)(__builtin_bit_cast(uint32_t, x) >> 16);
}

// 16x16x16 bf16 MFMA: builtin when the toolchain has it, else raw asm
__device__ __forceinline__ f32x4 mfma16(bf16x4 a, bf16x4 b, f32x4 c) {
#if __has_builtin(__builtin_amdgcn_mfma_f32_16x16x16bf16_1k)
    return __builtin_amdgcn_mfma_f32_16x16x16bf16_1k(a, b, c, 0, 0, 0);
#else
    asm("s_nop 1\n\tv_mfma_f32_16x16x16_bf16 %0, %1, %2, %0"
        : "+v"(c) : "v"(a), "v"(b));
    return c;
#endif
}

// async 16B/lane global->LDS: LDS dest = wave-uniform base + lane*16 (m104/m108)
__device__ __forceinline__ void async16(const short* g, const short* l) {
    __builtin_amdgcn_global_load_lds(
        (const __attribute__((address_space(1))) void*)(uintptr_t)(g),
        (__attribute__((address_space(3))) void*)(uintptr_t)(l),
        16, 0, 0);
}

// ---------------- prepass4: K + V only, XCD-local to the attn consumer -------
//  attn block with blockIdx.x = x reads pairs 4x..4x+3 -> convert pair p on
//  XCD p>>2 (linear id % 8 == XCD) so the 2 MB/XCD bf16 K+V stays in the
//  consumer's L2. Workspace format IDENTICAL to the verified v5 consumer:
//  K chunk c : row=c>>3, cc=(c&7)^(row&7) : K[row][cc*8 + j]   (XOR swizzle)
//  V chunk c = et*128 + a*64 + quad*16 + r16 :
//      j 0..3 -> V[a*32 + quad*4 + j][et*16 + r16]
//      j 4..7 -> V[a*32 + 16 + quad*4 + (j-4)][et*16 + r16]
__global__ __launch_bounds__(256) void prepass4(const float* __restrict__ qkv,
        short* __restrict__ kw, short* __restrict__ vw) {
    __shared__ float vt[64][68];   // vt[e][row]; 272 B rows -> 16B-aligned float4
    const int x = blockIdx.x;      // 1024 blocks
    const int xcd = x & 7, y = x >> 3;
    const int pairid = xcd * 4 + (y >> 5);   // matches attn's pairid = bx*4+k
    const int tile = y & 31;
    const int b = pairid >> 4, h = pairid & 15;
    const int tid = threadIdx.x;
    const int tg = pairid * 32 + tile;
    const float* base = qkv + (size_t)b * (L_SEQ * 3072) + (size_t)tile * 64 * 3072 + h * 64;
    short* ko = kw + (size_t)tg * 4096;
    short* vo = vw + (size_t)tg * 4096;

    // K (XOR-swizzled chunk order)
    #pragma unroll
    for (int it = 0; it < 2; ++it) {
        const int c = tid + it * 256;
        const int row = c >> 3, cc = (c & 7) ^ (row & 7);
        const float* src = base + (size_t)row * 3072 + 1024 + cc * 8;
        float4 a = *(const float4*)src, d = *(const float4*)(src + 4);
        short* o = ko + (size_t)c * 8;
        o[0] = f2bf(a.x); o[1] = f2bf(a.y); o[2] = f2bf(a.z); o[3] = f2bf(a.w);
        o[4] = f2bf(d.x); o[5] = f2bf(d.y); o[6] = f2bf(d.z); o[7] = f2bf(d.w);
    }
    // V: coalesced row reads -> transposed LDS
    {
        const int row = tid >> 2, e0 = (tid & 3) << 4;
        const float* src = base + (size_t)row * 3072 + 2048 + e0;
        #pragma unroll
        for (int q4 = 0; q4 < 4; ++q4) {
            float4 a = *(const float4*)(src + q4 * 4);
            vt[e0 + q4 * 4 + 0][row] = a.x;
            vt[e0 + q4 * 4 + 1][row] = a.y;
            vt[e0 + q4 * 4 + 2][row] = a.z;
            vt[e0 + q4 * 4 + 3][row] = a.w;
        }
    }
    __syncthreads();
    #pragma unroll
    for (int it = 0; it < 2; ++it) {
        const int c = tid + it * 256;
        const int et = c >> 7, a = (c >> 6) & 1, l6 = c & 63;
        const int quad = l6 >> 4, r16 = l6 & 15;
        const int e = et * 16 + r16;
        float4 x0 = *(const float4*)&vt[e][a * 32 + quad * 4];
        float4 x1 = *(const float4*)&vt[e][a * 32 + 16 + quad * 4];
        bf16x8 o8;
        o8[0] = f2bf(x0.x); o8[1] = f2bf(x0.y); o8[2] = f2bf(x0.z); o8[3] = f2bf(x0.w);
        o8[4] = f2bf(x1.x); o8[5] = f2bf(x1.y); o8[6] = f2bf(x1.z); o8[7] = f2bf(x1.w);
        *(bf16x8*)(vo + (size_t)c * 8) = o8;
    }
}

// ---------------- attention v5 (best measured: 111.5 us total) ----------------
// Grid (8,128), 4 blocks/CU, exactly resident (no refill). XCD round-robin by
// linear id => XCD = blockIdx.x, CU slot = y%32, co-resident k = y>>5 in 0..3.
// qtile(k,s) = {s, 31-s, (s+16)&31, (15-s)&31}: each a permutation of 0..31
// (coverage), and sum of tile-counts n(t)=min(t,16)+1 over k is exactly 51
// for every s -> perfectly balanced per-CU makespan.
// Rounds 1-7 post-mortem: LDS-reuse (v6/v7), counted-vmcnt (v8b), dynamic
// queue (v10), and zero-barrier waveflash (v12) all landed at or above this
// kernel's total; every pipe counter idle in all variants -> the ~38us attn
// floor is a latency invariant none of the schedule families moved. This is
// the verified best configuration.
__global__ __launch_bounds__(256, 4) void flexattn_fwd5(
        const float* __restrict__ qkv, const short* __restrict__ kw,
        const short* __restrict__ vw, float* __restrict__ out) {
    __shared__ __align__(16) short kS[2][4096];
    __shared__ __align__(16) short vS[2][4096];

    const int s = blockIdx.y & 31;
    const int k = blockIdx.y >> 5;
    const int t16 = (s + ((k >> 1) << 4)) & 31;
    const int qtile = (k & 1) ? (31 - t16) : t16;
    const int pairid = blockIdx.x * 4 + k;          // blockIdx.x = XCD slot
    const int h = pairid & 15;
    const int b = pairid >> 4;

    const int tid  = threadIdx.x;
    const int w    = tid >> 6;
    const int lane = tid & 63;
    const int quad = lane >> 4;
    const int r16  = lane & 15;
    const int qb   = qtile * QT;
    const int bh32 = (b * NH + h) * 32;
    const int q    = qb + w * 16 + r16;   // this lane's query (fixed)

    const int t0q = (qb >= WINDOW - 1) ? ((qb - (WINDOW - 1)) >> 6) : 0;
    const int t1  = qtile;
    const int swz = quad ^ (r16 & 7);
    const int cb0 = w * 128;

    // prefetch first K/V tile into buf 0
    {
        const short* ktile = kw + (size_t)(bh32 + t0q) * 4096;
        const short* vtile = vw + (size_t)(bh32 + t0q) * 4096;
        async16(ktile + (size_t)(cb0 + lane) * 8,      &kS[0][cb0 * 8]);
        async16(ktile + (size_t)(cb0 + 64 + lane) * 8, &kS[0][(cb0 + 64) * 8]);
        async16(vtile + (size_t)(cb0 + lane) * 8,      &vS[0][cb0 * 8]);
        async16(vtile + (size_t)(cb0 + 64 + lane) * 8, &vS[0][(cb0 + 64) * 8]);
    }

    // Q fragments from fp32 (B-operand: Q[n=q=r16][k=e=quad*8+j]), scale*log2e folded
    const float qscale = 0.125f * LOG2E;
    bf16x8 qfrag[2];
    {
        const float* qrow = qkv + (size_t)b * (L_SEQ * 3072) + (size_t)q * 3072 + h * 64;
        #pragma unroll
        for (int es = 0; es < 2; ++es) {
            const float* p = qrow + es * 32 + quad * 8;
            float4 a = *(const float4*)p;
            float4 c = *(const float4*)(p + 4);
            bf16x8 f;
            f[0] = f2bf(a.x * qscale); f[1] = f2bf(a.y * qscale);
            f[2] = f2bf(a.z * qscale); f[3] = f2bf(a.w * qscale);
            f[4] = f2bf(c.x * qscale); f[5] = f2bf(c.y * qscale);
            f[6] = f2bf(c.z * qscale); f[7] = f2bf(c.w * qscale);
            qfrag[es] = f;
        }
    }

    const float slope2 = __builtin_amdgcn_exp2f(-8.0f * (float)(h + 1) / (float)NH) * LOG2E;
    // E[ct*4+r] = slope2*(key - q) - M_FIX for key = ct*16 + quad*4 + r (tile-local)
    float E[16];
    #pragma unroll
    for (int ct = 0; ct < 4; ++ct)
        #pragma unroll
        for (int r = 0; r < 4; ++r)
            E[ct * 4 + r] = slope2 * (float)(ct * 16 + quad * 4 + r - q) - M_FIX;

    f32x4 O[4] = {{0,0,0,0},{0,0,0,0},{0,0,0,0},{0,0,0,0}};  // O^T: e=et*16+quad*4+r, col q
    float rs = 0.f;

    for (int kt = t0q; kt <= t1; ++kt) {
        const int cur = (kt - t0q) & 1;
        __syncthreads();   // drains DMA(kt) + protects buf cur^1 for prefetch
        if (kt < t1) {
            const int nb = cur ^ 1;
            const short* ktile = kw + (size_t)(bh32 + kt + 1) * 4096;
            const short* vtile = vw + (size_t)(bh32 + kt + 1) * 4096;
            async16(ktile + (size_t)(cb0 + lane) * 8,      &kS[nb][cb0 * 8]);
            async16(ktile + (size_t)(cb0 + 64 + lane) * 8, &kS[nb][(cb0 + 64) * 8]);
            async16(vtile + (size_t)(cb0 + lane) * 8,      &vS[nb][cb0 * 8]);
            async16(vtile + (size_t)(cb0 + 64 + lane) * 8, &vS[nb][(cb0 + 64) * 8]);
        }

        // S^T = K Q^T : C[m=key=ct*16+quad*4+r, n=q=r16]
        f32x4 S[4];
        #pragma unroll
        for (int ct = 0; ct < 4; ++ct) {
            const int c0 = ((ct * 16 + r16) << 3) + swz;
            bf16x8 k0 = *(const bf16x8*)&kS[cur][c0 * 8];        // e in [quad*8,+8)
            bf16x8 k1 = *(const bf16x8*)&kS[cur][(c0 ^ 4) * 8];  // e in [32+quad*8,+8)
            f32x4 acc = {0.f, 0.f, 0.f, 0.f};
            acc = __builtin_amdgcn_mfma_f32_16x16x32_bf16(k0, qfrag[0], acc, 0, 0, 0);
            acc = __builtin_amdgcn_mfma_f32_16x16x32_bf16(k1, qfrag[1], acc, 0, 0, 0);
            S[ct] = acc;
        }

        // p = exp2(S^T + E + At); lands directly in PV B-fragment layout (no cross-lane)
        const float At = slope2 * (float)(kt * 64);
        bf16x4 pb[4];
        if (kt != t0q && kt != t1) {          // middle tiles: no mask possible
            #pragma unroll
            for (int ct = 0; ct < 4; ++ct)
                #pragma unroll
                for (int r = 0; r < 4; ++r) {
                    const float pe = __builtin_amdgcn_exp2f(S[ct][r] + E[ct * 4 + r] + At);
                    rs += pe;
                    pb[ct][r] = f2bf_trunc(pe);
                }
        } else {                               // first tile (dist>=W) / diagonal (dist<0)
            const int key0 = kt * 64 + quad * 4;
            #pragma unroll
            for (int ct = 0; ct < 4; ++ct)
                #pragma unroll
                for (int r = 0; r < 4; ++r) {
                    const int dist = q - (key0 + ct * 16 + r);
                    float pe = __builtin_amdgcn_exp2f(S[ct][r] + E[ct * 4 + r] + At);
                    pe = (dist < 0 || dist >= WINDOW) ? 0.0f : pe;
                    rs += pe;
                    pb[ct][r] = f2bf_trunc(pe);
                }
        }

        // O^T += V^T P^T : A = V K=16 fragment (one b128 feeds two MFMAs), B = pb
        #pragma unroll
        for (int et = 0; et < 4; ++et) {
            #pragma unroll
            for (int a = 0; a < 2; ++a) {
                bf16x8 v8 = *(const bf16x8*)&vS[cur][(size_t)((et * 2 + a) * 64 + lane) * 8];
                bf16x4 vlo = {v8[0], v8[1], v8[2], v8[3]};
                bf16x4 vhi = {v8[4], v8[5], v8[6], v8[7]};
                O[et] = mfma16(vlo, pb[a * 2 + 0], O[et]);
                O[et] = mfma16(vhi, pb[a * 2 + 1], O[et]);
            }
        }
    }

    // final row-sum: lanes {quad 0..3} x same r16 share q
    rs += __shfl_xor(rs, 16, 64);
    rs += __shfl_xor(rs, 32, 64);
    const float rl = 1.0f / rs;

    // epilogue: out[b,q,h,e]; e = et*16 + quad*4 + r -> float4 stores
    float* op = out + ((size_t)b * L_SEQ + q) * (NH * EDIM) + h * EDIM;
    #pragma unroll
    for (int et = 0; et < 4; ++et) {
        float4 o4 = {O[et][0] * rl, O[et][1] * rl, O[et][2] * rl, O[et][3] * rl};
        *(float4*)(op + et * 16 + quad * 4) = o4;
    }
}

// ---------------- fallback (no workspace): round-1 style, fp32 in-kernel staging ----------------
__global__ __launch_bounds__(256, 2) void flexattn_fwd_fb(
        const float* __restrict__ qkv, float* __restrict__ out) {
    __shared__ __align__(16) short kT[KT * 72];
    __shared__ __align__(16) short vB[8 * 64 * 8];
    __shared__ __align__(16) short pT[4][16 * 72];

    const int qtile = blockIdx.x;
    const int h     = blockIdx.y;
    const int b     = blockIdx.z;
    const int tid   = threadIdx.x;
    const int w     = tid >> 6;
    const int lane  = tid & 63;
    const int quad  = lane >> 4;
    const int r16   = lane & 15;
    const int qb = qtile * QT;
    const int rowstride = 3 * NH * EDIM;

    const float* qbase = qkv + ((size_t)b * L_SEQ * 3 + 0) * (NH * EDIM) + h * EDIM;
    const float* kbase = qkv + ((size_t)b * L_SEQ * 3 + 1) * (NH * EDIM) + h * EDIM;
    const float* vbase = qkv + ((size_t)b * L_SEQ * 3 + 2) * (NH * EDIM) + h * EDIM;

    const float qscale = 0.125f * LOG2E;
    bf16x8 qfrag[2];
    {
        const int qg = qb + w * 16 + r16;
        const float* qrow = qbase + (size_t)qg * rowstride;
        #pragma unroll
        for (int es = 0; es < 2; ++es) {
            const float* p = qrow + es * 32 + quad * 8;
            float4 a = *(const float4*)p;
            float4 c = *(const float4*)(p + 4);
            bf16x8 f;
            f[0] = f2bf(a.x * qscale); f[1] = f2bf(a.y * qscale);
            f[2] = f2bf(a.z * qscale); f[3] = f2bf(a.w * qscale);
            f[4] = f2bf(c.x * qscale); f[5] = f2bf(c.y * qscale);
            f[6] = f2bf(c.z * qscale); f[7] = f2bf(c.w * qscale);
            qfrag[es] = f;
        }
    }

    const float slope2 = __builtin_amdgcn_exp2f(-8.0f * (float)(h + 1) / (float)NH) * LOG2E;
    f32x4 O[4] = {{0,0,0,0},{0,0,0,0},{0,0,0,0},{0,0,0,0}};
    float m_run[4] = {-1e30f, -1e30f, -1e30f, -1e30f};
    float l_run[4] = {0.f, 0.f, 0.f, 0.f};

    const int kmin = (qb >= WINDOW - 1) ? (qb - (WINDOW - 1)) : 0;
    const int t0 = kmin >> 6;
    const int t1 = qtile;

    for (int kt = t0; kt <= t1; ++kt) {
        __syncthreads();
        {
            const int j = tid >> 2;
            const int ebase = (tid & 3) * 16;
            const float* krow = kbase + (size_t)(kt * KT + j) * rowstride + ebase;
            const float* vrow = vbase + (size_t)(kt * KT + j) * rowstride + ebase;
            const int js = j >> 5, qd = (j >> 3) & 3, ii = j & 7;
            #pragma unroll
            for (int ee = 0; ee < 4; ++ee) {
                const int e = ebase + ee * 4;
                float4 k4 = *(const float4*)(krow + ee * 4);
                short* kd = &kT[j * 72 + e];
                kd[0] = f2bf(k4.x); kd[1] = f2bf(k4.y);
                kd[2] = f2bf(k4.z); kd[3] = f2bf(k4.w);
                float4 v4 = *(const float4*)(vrow + ee * 4);
                const int et = e >> 4;
                const int ln = qd * 16 + (e & 15);
                short* vd = &vB[(((js * 4 + et) * 64) + ln) * 8 + ii];
                vd[0]  = f2bf(v4.x);
                vd[8]  = f2bf(v4.y);
                vd[16] = f2bf(v4.z);
                vd[24] = f2bf(v4.w);
            }
        }
        __syncthreads();

        f32x4 S[4];
        #pragma unroll
        for (int ct = 0; ct < 4; ++ct) {
            const short* kr = &kT[(ct * 16 + r16) * 72 + quad * 8];
            bf16x8 b0 = *(const bf16x8*)kr;
            bf16x8 b1 = *(const bf16x8*)(kr + 32);
            f32x4 acc = {0.f, 0.f, 0.f, 0.f};
            acc = __builtin_amdgcn_mfma_f32_16x16x32_bf16(qfrag[0], b0, acc, 0, 0, 0);
            acc = __builtin_amdgcn_mfma_f32_16x16x32_bf16(qfrag[1], b1, acc, 0, 0, 0);
            S[ct] = acc;
        }

        const int q0 = qb + w * 16 + quad * 4;
        float p[4][4];
        float mt[4] = {-1e30f, -1e30f, -1e30f, -1e30f};
        #pragma unroll
        for (int ct = 0; ct < 4; ++ct) {
            const int kg = kt * KT + ct * 16 + r16;
            #pragma unroll
            for (int r = 0; r < 4; ++r) {
                const int dist = q0 + r - kg;
                float s2 = S[ct][r] - slope2 * (float)dist;
                if (dist < 0 || dist >= WINDOW) s2 = -1e30f;
                p[ct][r] = s2;
                mt[r] = fmaxf(mt[r], s2);
            }
        }
        #pragma unroll
        for (int d = 1; d < 16; d <<= 1) {
            #pragma unroll
            for (int r = 0; r < 4; ++r)
                mt[r] = fmaxf(mt[r], __shfl_xor(mt[r], d, 64));
        }

        float alpha[4], rsum[4];
        #pragma unroll
        for (int r = 0; r < 4; ++r) {
            const float mn = fmaxf(m_run[r], mt[r]);
            alpha[r] = __builtin_amdgcn_exp2f(m_run[r] - mn);
            m_run[r] = mn;
            float sacc = 0.f;
            #pragma unroll
            for (int ct = 0; ct < 4; ++ct) {
                const float pe = __builtin_amdgcn_exp2f(p[ct][r] - mn);
                p[ct][r] = pe;
                sacc += pe;
            }
            rsum[r] = sacc;
        }
        #pragma unroll
        for (int d = 1; d < 16; d <<= 1) {
            #pragma unroll
            for (int r = 0; r < 4; ++r)
                rsum[r] += __shfl_xor(rsum[r], d, 64);
        }
        #pragma unroll
        for (int r = 0; r < 4; ++r)
            l_run[r] = l_run[r] * alpha[r] + rsum[r];
        #pragma unroll
        for (int et = 0; et < 4; ++et) {
            #pragma unroll
            for (int r = 0; r < 4; ++r)
                O[et][r] *= alpha[r];
        }

        short* pw = &pT[w][0];
        #pragma unroll
        for (int ct = 0; ct < 4; ++ct) {
            #pragma unroll
            for (int r = 0; r < 4; ++r)
                pw[(quad * 4 + r) * 72 + ct * 16 + r16] = f2bf(p[ct][r]);
        }
        bf16x8 aP0 = *(const bf16x8*)(pw + r16 * 72 + quad * 8);
        bf16x8 aP1 = *(const bf16x8*)(pw + r16 * 72 + 32 + quad * 8);

        #pragma unroll
        for (int et = 0; et < 4; ++et) {
            bf16x8 v0 = *(const bf16x8*)(&vB[((0 * 4 + et) * 64 + lane) * 8]);
            O[et] = __builtin_amdgcn_mfma_f32_16x16x32_bf16(aP0, v0, O[et], 0, 0, 0);
            bf16x8 v1 = *(const bf16x8*)(&vB[((1 * 4 + et) * 64 + lane) * 8]);
            O[et] = __builtin_amdgcn_mfma_f32_16x16x32_bf16(aP1, v1, O[et], 0, 0, 0);
        }
    }

    float* obase = out + (((size_t)b * L_SEQ) * NH + (size_t)h) * EDIM;
    #pragma unroll
    for (int r = 0; r < 4; ++r) {
        const int qg = qb + w * 16 + quad * 4 + r;
        const float rl = 1.0f / l_run[r];
        float* orow = obase + (size_t)qg * (NH * EDIM);
        #pragma unroll
        for (int et = 0; et < 4; ++et)
            orow[et * 16 + r16] = O[et][r] * rl;
    }
}

extern "C" void kernel_launch(void* const* d_in, const int* in_sizes, int n_in,
                              void* d_out, int out_size, void* d_ws, size_t ws_size,
                              hipStream_t stream) {
    const float* qkv = (const float*)d_in[0];
    float* out = (float*)d_out;
    const size_t need = (size_t)2 * 1024 * 4096 * sizeof(short);  // K + V, 16.8 MB
    if (ws_size >= need) {
        short* kw = (short*)d_ws;
        short* vw = kw + (size_t)1024 * 4096;
        prepass4<<<1024, 256, 0, stream>>>(qkv, kw, vw);
        dim3 grid(8, 128);
        flexattn_fwd5<<<grid, 256, 0, stream>>>(qkv, kw, vw, out);
    } else {
        dim3 gridfb(L_SEQ / QT, NH, 2);
        flexattn_fwd_fb<<<gridfb, 256, 0, stream>>>(qkv, out);
    }
}